// Round 1
// baseline (8981.228 us; speedup 1.0000x reference)
//
#include <hip/hip_runtime.h>
#include <hip/hip_bf16.h>

#define KD 128

__device__ __forceinline__ unsigned fenc(float x){
  unsigned u = __float_as_uint(x);
  return (u & 0x80000000u) ? ~u : (u | 0x80000000u);
}
__device__ __forceinline__ float fdec(unsigned e){
  return __uint_as_float((e & 0x80000000u) ? (e ^ 0x80000000u) : ~e);
}
__device__ __forceinline__ void atomAddF(float* p, float v){
  unsafeAtomicAdd(p, v);
}

// ---------------- generic K=128 GEMM: C = act(A1[idx]@W1 (+A2[idx]@W2) (+bias)) (+Res[ridx]) ----
template<int NC, bool HAS_A2, bool HAS_BIAS, bool DO_ELU, bool HAS_RES>
__global__ __launch_bounds__(256) void gemm_k128(
    const float* __restrict__ A1, const float* __restrict__ W1,
    const float* __restrict__ A2, const float* __restrict__ W2,
    const float* __restrict__ bias, const float* __restrict__ Res,
    const int* __restrict__ aidx, const int* __restrict__ ridx,
    int M, float* __restrict__ C)
{
  constexpr int CW = NC / 16;           // cols per thread (8 for NC=128, 4 for NC=64)
  __shared__ float sA[64][KD + 4];      // +4 pad: avoid same-bank rows
  __shared__ float sW[KD][NC];
  const int t  = threadIdx.x;
  const int ty = t >> 4, tx = t & 15;
  const int row0 = blockIdx.x * 64;

  float acc[4][CW];
  #pragma unroll
  for (int i = 0; i < 4; ++i)
    #pragma unroll
    for (int j = 0; j < CW; ++j) acc[i][j] = 0.f;

  const int npass = HAS_A2 ? 2 : 1;
  for (int pass = 0; pass < npass; ++pass) {
    const float* Am = (pass == 0) ? A1 : A2;
    const float* Wm = (pass == 0) ? W1 : W2;
    if (pass == 1) __syncthreads();     // protect LDS reuse
    // stage W tile (KD x NC)
    #pragma unroll
    for (int p = t; p < KD * NC / 4; p += 256) {
      reinterpret_cast<float4*>(&sW[0][0])[p] = reinterpret_cast<const float4*>(Wm)[p];
    }
    // stage A tile (64 x KD), gathered rows, guarded tail
    #pragma unroll
    for (int p = t; p < 64 * (KD / 4); p += 256) {
      int r  = p >> 5;                  // p / 32
      int c4 = p & 31;
      float4 v = make_float4(0.f, 0.f, 0.f, 0.f);
      int gr = row0 + r;
      if (gr < M) {
        long grow = aidx ? (long)aidx[gr] : (long)gr;
        v = reinterpret_cast<const float4*>(Am + grow * KD)[c4];
      }
      *reinterpret_cast<float4*>(&sA[r][c4 * 4]) = v;
    }
    __syncthreads();
    #pragma unroll 4
    for (int k = 0; k < KD; ++k) {
      float a[4], wv[CW];
      #pragma unroll
      for (int i = 0; i < 4; ++i) a[i] = sA[ty * 4 + i][k];
      #pragma unroll
      for (int j = 0; j < CW; ++j) wv[j] = sW[k][tx * CW + j];
      #pragma unroll
      for (int i = 0; i < 4; ++i)
        #pragma unroll
        for (int j = 0; j < CW; ++j)
          acc[i][j] = fmaf(a[i], wv[j], acc[i][j]);
    }
  }
  // epilogue
  #pragma unroll
  for (int i = 0; i < 4; ++i) {
    int gr = row0 + ty * 4 + i;
    if (gr >= M) continue;
    long rrow = 0;
    if (HAS_RES) rrow = ridx ? (long)ridx[gr] : (long)gr;
    #pragma unroll
    for (int j = 0; j < CW; ++j) {
      int c = tx * CW + j;
      float v = acc[i][j];
      if (HAS_BIAS) v += bias[c];
      if (DO_ELU) v = (v > 0.f) ? v : (__expf(v) - 1.f);
      if (HAS_RES) v += Res[rrow * NC + c];
      C[(long)gr * NC + c] = v;
    }
  }
}

// ---------------- per-node score projections: as = H1@a_s, an = H1@a_n -------------
__global__ __launch_bounds__(256) void proj_kernel(
    const float* __restrict__ H1, const float* __restrict__ a_s, const float* __restrict__ a_n,
    float* __restrict__ as_o, float* __restrict__ an_o, int M)
{
  int wid  = (int)((blockIdx.x * 256 + threadIdx.x) >> 6);
  int lane = threadIdx.x & 63;
  if (wid >= M) return;
  float2 h  = *reinterpret_cast<const float2*>(H1 + (long)wid * KD + lane * 2);
  float2 vs = *reinterpret_cast<const float2*>(a_s + lane * 2);
  float2 vn = *reinterpret_cast<const float2*>(a_n + lane * 2);
  float ps = h.x * vs.x + h.y * vs.y;
  float pn = h.x * vn.x + h.y * vn.y;
  #pragma unroll
  for (int o = 32; o > 0; o >>= 1) { ps += __shfl_xor(ps, o, 64); pn += __shfl_xor(pn, o, 64); }
  if (lane == 0) { as_o[wid] = ps; an_o[wid] = pn; }
}

// ---------------- needed-dst flags -------------
__global__ void flags_kernel(const int* __restrict__ ui, const int* __restrict__ ii, int B,
                             int* __restrict__ nfu, int* __restrict__ nfb)
{
  int i = blockIdx.x * blockDim.x + threadIdx.x;
  if (i < B) { nfu[ui[i]] = 1; nfb[ii[i]] = 1; }
}

// ---------------- omega edge weights -------------
__global__ void uw_kernel(const float* __restrict__ gc, const float* __restrict__ omega,
                          int E, float* __restrict__ uw)
{
  int e = blockIdx.x * blockDim.x + threadIdx.x;
  if (e < E) uw[e] = gc[(long)e*3+0]*omega[0] + gc[(long)e*3+1]*omega[1] + gc[(long)e*3+2]*omega[2];
}

__device__ __forceinline__ float edge_score(int s, int d, int e,
    const float* as_, const float* an_, const float* uw)
{
  float sc = as_[d] + an_[s];
  if (uw) sc *= uw[e];
  return (sc >= 0.f) ? sc : 0.2f * sc;   // leaky_relu 0.2
}

// ---------------- pass A: segment max -------------
__global__ __launch_bounds__(256) void edge_max(
    const int* __restrict__ src, const int* __restrict__ dst,
    const float* __restrict__ as_, const float* __restrict__ an_,
    const float* __restrict__ uw, const int* __restrict__ flag,
    unsigned* __restrict__ menc, int E)
{
  int e = blockIdx.x * blockDim.x + threadIdx.x;
  if (e >= E) return;
  int d = dst[e];
  if (!flag[d]) return;
  float sc = edge_score(src[e], d, e, as_, an_, uw);
  atomicMax(&menc[d], fenc(sc));
}

// ---------------- pass B: exp + segment sum -------------
__global__ __launch_bounds__(256) void edge_exp(
    const int* __restrict__ src, const int* __restrict__ dst,
    const float* __restrict__ as_, const float* __restrict__ an_,
    const float* __restrict__ uw, const int* __restrict__ flag,
    const unsigned* __restrict__ menc, float* __restrict__ ssum,
    float* __restrict__ p, int E)
{
  int e = blockIdx.x * blockDim.x + threadIdx.x;
  if (e >= E) return;
  int d = dst[e];
  if (!flag[d]) return;
  float sc = edge_score(src[e], d, e, as_, an_, uw);
  float ev = __expf(sc - fdec(menc[d]));
  p[e] = ev;
  atomAddF(&ssum[d], ev);
}

// ---------------- pass C: weighted aggregation -------------
__global__ __launch_bounds__(256) void edge_aggr(
    const int* __restrict__ src, const int* __restrict__ dst,
    const int* __restrict__ flag, const float* __restrict__ p,
    const float* __restrict__ ssum, const float* __restrict__ H1,
    float* __restrict__ Hout, int E)
{
  long gid = (long)blockIdx.x * blockDim.x + threadIdx.x;
  int e = (int)(gid >> 2);
  if (e >= E) return;
  int d = dst[e];
  if (!flag[d]) return;
  int chunk = (int)(gid & 3);
  float alpha = p[e] / ssum[d];
  const float4* hs = reinterpret_cast<const float4*>(H1 + (long)src[e] * KD + chunk * 32);
  float* outp = Hout + (long)d * KD + chunk * 32;
  #pragma unroll
  for (int j = 0; j < 8; ++j) {
    float4 h = hs[j];
    atomAddF(outp + j*4+0, h.x * alpha);
    atomAddF(outp + j*4+1, h.y * alpha);
    atomAddF(outp + j*4+2, h.z * alpha);
    atomAddF(outp + j*4+3, h.w * alpha);
  }
}

// ---------------- final: dot + biases + sigmoid -------------
__global__ __launch_bounds__(256) void final_kernel(
    const float* __restrict__ Ug, const float* __restrict__ Bg,
    const int* __restrict__ ui, const int* __restrict__ ii,
    const float* __restrict__ bias_u, const float* __restrict__ bias_b,
    const float* __restrict__ bx, float* __restrict__ out, int B)
{
  int wid  = (int)((blockIdx.x * 256 + threadIdx.x) >> 6);
  int lane = threadIdx.x & 63;
  if (wid >= B) return;
  float v = Ug[(long)wid * 64 + lane] * Bg[(long)wid * 64 + lane];
  #pragma unroll
  for (int o = 32; o > 0; o >>= 1) v += __shfl_xor(v, o, 64);
  if (lane == 0) {
    float raw = v + bias_u[ui[wid]] + bias_b[ii[wid]] + bx[0];
    out[wid] = 4.f / (1.f + __expf(-raw)) + 1.f;
  }
}

extern "C" void kernel_launch(void* const* d_in, const int* in_sizes, int n_in,
                              void* d_out, int out_size, void* d_ws, size_t ws_size,
                              hipStream_t stream)
{
  const int*   ui    = (const int*)  d_in[0];
  const int*   ii    = (const int*)  d_in[1];
  const float* S_u   = (const float*)d_in[2];
  const float* S_b   = (const float*)d_in[3];
  const int*   eu    = (const int*)  d_in[4];
  const int*   eb    = (const int*)  d_in[5];
  const float* gc    = (const float*)d_in[6];
  const float* W1_u  = (const float*)d_in[7];
  const float* a_s_u = (const float*)d_in[8];
  const float* a_n_u = (const float*)d_in[9];
  const float* W1_b  = (const float*)d_in[10];
  const float* a_s_b = (const float*)d_in[11];
  const float* a_n_b = (const float*)d_in[12];
  const float* omega = (const float*)d_in[13];
  const float* W_u2  = (const float*)d_in[14];
  const float* W_us2w= (const float*)d_in[15];
  const float* W_us2b= (const float*)d_in[16];
  const float* W_b2  = (const float*)d_in[17];
  const float* W_bs2w= (const float*)d_in[18];
  const float* W_bs2b= (const float*)d_in[19];
  const float* W_u3  = (const float*)d_in[20];
  const float* W_b3  = (const float*)d_in[21];
  const float* H_u4  = (const float*)d_in[22];
  const float* H_b4  = (const float*)d_in[23];
  const float* bias_u= (const float*)d_in[24];
  const float* bias_b= (const float*)d_in[25];
  const float* b_x   = (const float*)d_in[26];
  float* out = (float*)d_out;

  const int B  = in_sizes[0];
  const int NU = in_sizes[2] / KD;
  const int NI = in_sizes[3] / KD;
  const int EU = in_sizes[4] / 2;
  const int EB = in_sizes[5] / 2;

  char* w = (char*)d_ws;
  auto alloc = [&](size_t bytes) -> void* {
    void* r = (void*)w;
    w += (bytes + 255) & ~(size_t)255;
    return r;
  };
  // ---- zero-initialized region (one memset per call) ----
  unsigned* m_u = (unsigned*)alloc((size_t)NU * 4);
  float*    s_u = (float*)   alloc((size_t)NU * 4);
  unsigned* m_b = (unsigned*)alloc((size_t)NI * 4);
  float*    s_b = (float*)   alloc((size_t)NI * 4);
  int*      nfu = (int*)     alloc((size_t)NU * 4);
  int*      nfb = (int*)     alloc((size_t)NI * 4);
  float*    Hu2 = (float*)   alloc((size_t)NU * KD * 4);
  float*    Hb2 = (float*)   alloc((size_t)NI * KD * 4);
  size_t zbytes = (size_t)(w - (char*)d_ws);
  // ---- scratch (fully written before read) ----
  float* H1u  = (float*)alloc((size_t)NU * KD * 4);
  float* H1b  = (float*)alloc((size_t)NI * KD * 4);
  float* asu  = (float*)alloc((size_t)NU * 4);
  float* anu  = (float*)alloc((size_t)NU * 4);
  float* asb  = (float*)alloc((size_t)NI * 4);
  float* anb  = (float*)alloc((size_t)NI * 4);
  float* uwv  = (float*)alloc((size_t)EB * 4);
  float* p_u  = (float*)alloc((size_t)EU * 4);
  float* p_b  = (float*)alloc((size_t)EB * 4);
  float* Hu3g = (float*)alloc((size_t)B * KD * 4);
  float* Hb3g = (float*)alloc((size_t)B * KD * 4);
  float* Ug   = (float*)alloc((size_t)B * 64 * 4);
  float* Bg   = (float*)alloc((size_t)B * 64 * 4);
  (void)ws_size; (void)n_in; (void)out_size;

  hipMemsetAsync(d_ws, 0, zbytes, stream);

  flags_kernel<<<(B + 255) / 256, 256, 0, stream>>>(ui, ii, B, nfu, nfb);
  uw_kernel<<<(EB + 255) / 256, 256, 0, stream>>>(gc, omega, EB, uwv);

  gemm_k128<128,false,false,false,false><<<(NU + 63) / 64, 256, 0, stream>>>(
      S_u, W1_u, nullptr, nullptr, nullptr, nullptr, nullptr, nullptr, NU, H1u);
  gemm_k128<128,false,false,false,false><<<(NI + 63) / 64, 256, 0, stream>>>(
      S_b, W1_b, nullptr, nullptr, nullptr, nullptr, nullptr, nullptr, NI, H1b);

  proj_kernel<<<(NU + 3) / 4, 256, 0, stream>>>(H1u, a_s_u, a_n_u, asu, anu, NU);
  proj_kernel<<<(NI + 3) / 4, 256, 0, stream>>>(H1b, a_s_b, a_n_b, asb, anb, NI);

  edge_max<<<(EU + 255) / 256, 256, 0, stream>>>(eu, eu + EU, asu, anu, nullptr, nfu, m_u, EU);
  edge_max<<<(EB + 255) / 256, 256, 0, stream>>>(eb, eb + EB, asb, anb, uwv, nfb, m_b, EB);
  edge_exp<<<(EU + 255) / 256, 256, 0, stream>>>(eu, eu + EU, asu, anu, nullptr, nfu, m_u, s_u, p_u, EU);
  edge_exp<<<(EB + 255) / 256, 256, 0, stream>>>(eb, eb + EB, asb, anb, uwv, nfb, m_b, s_b, p_b, EB);
  edge_aggr<<<(int)(((long)EU * 4 + 255) / 256), 256, 0, stream>>>(eu, eu + EU, nfu, p_u, s_u, H1u, Hu2, EU);
  edge_aggr<<<(int)(((long)EB * 4 + 255) / 256), 256, 0, stream>>>(eb, eb + EB, nfb, p_b, s_b, H1b, Hb2, EB);

  gemm_k128<128,true,true,true,false><<<(B + 63) / 64, 256, 0, stream>>>(
      Hu2, W_u2, S_u, W_us2w, W_us2b, nullptr, ui, nullptr, B, Hu3g);
  gemm_k128<128,true,true,true,false><<<(B + 63) / 64, 256, 0, stream>>>(
      Hb2, W_b2, S_b, W_bs2w, W_bs2b, nullptr, ii, nullptr, B, Hb3g);

  gemm_k128<64,false,false,true,true><<<(B + 63) / 64, 256, 0, stream>>>(
      Hu3g, W_u3, nullptr, nullptr, nullptr, H_u4, nullptr, ui, B, Ug);
  gemm_k128<64,false,false,true,true><<<(B + 63) / 64, 256, 0, stream>>>(
      Hb3g, W_b3, nullptr, nullptr, nullptr, H_b4, nullptr, ii, B, Bg);

  final_kernel<<<(B + 3) / 4, 256, 0, stream>>>(Ug, Bg, ui, ii, bias_u, bias_b, b_x, out, B);
}

// Round 2
// 614.028 us; speedup vs baseline: 14.6267x; 14.6267x over previous
//
#include <hip/hip_runtime.h>
#include <hip/hip_bf16.h>

#define KD 128

// ---------------- generic K=128 GEMM: C = act(A1[idx]@W1 (+A2[idx]@W2) (+bias)) (+Res[ridx]) ----
template<int NC, bool HAS_A2, bool HAS_BIAS, bool DO_ELU, bool HAS_RES>
__global__ __launch_bounds__(256) void gemm_k128(
    const float* __restrict__ A1, const float* __restrict__ W1,
    const float* __restrict__ A2, const float* __restrict__ W2,
    const float* __restrict__ bias, const float* __restrict__ Res,
    const int* __restrict__ aidx, const int* __restrict__ ridx,
    int M, float* __restrict__ C)
{
  constexpr int CW = NC / 16;           // cols per thread (8 for NC=128, 4 for NC=64)
  __shared__ float sA[64][KD + 4];      // +4 pad: avoid same-bank rows
  __shared__ float sW[KD][NC];
  const int t  = threadIdx.x;
  const int ty = t >> 4, tx = t & 15;
  const int row0 = blockIdx.x * 64;

  float acc[4][CW];
  #pragma unroll
  for (int i = 0; i < 4; ++i)
    #pragma unroll
    for (int j = 0; j < CW; ++j) acc[i][j] = 0.f;

  const int npass = HAS_A2 ? 2 : 1;
  for (int pass = 0; pass < npass; ++pass) {
    const float* Am = (pass == 0) ? A1 : A2;
    const float* Wm = (pass == 0) ? W1 : W2;
    if (pass == 1) __syncthreads();     // protect LDS reuse
    // stage W tile (KD x NC)
    #pragma unroll
    for (int p = t; p < KD * NC / 4; p += 256) {
      reinterpret_cast<float4*>(&sW[0][0])[p] = reinterpret_cast<const float4*>(Wm)[p];
    }
    // stage A tile (64 x KD), gathered rows, guarded tail
    #pragma unroll
    for (int p = t; p < 64 * (KD / 4); p += 256) {
      int r  = p >> 5;                  // p / 32
      int c4 = p & 31;
      float4 v = make_float4(0.f, 0.f, 0.f, 0.f);
      int gr = row0 + r;
      if (gr < M) {
        long grow = aidx ? (long)aidx[gr] : (long)gr;
        v = reinterpret_cast<const float4*>(Am + grow * KD)[c4];
      }
      *reinterpret_cast<float4*>(&sA[r][c4 * 4]) = v;
    }
    __syncthreads();
    #pragma unroll 4
    for (int k = 0; k < KD; ++k) {
      float a[4], wv[CW];
      #pragma unroll
      for (int i = 0; i < 4; ++i) a[i] = sA[ty * 4 + i][k];
      #pragma unroll
      for (int j = 0; j < CW; ++j) wv[j] = sW[k][tx * CW + j];
      #pragma unroll
      for (int i = 0; i < 4; ++i)
        #pragma unroll
        for (int j = 0; j < CW; ++j)
          acc[i][j] = fmaf(a[i], wv[j], acc[i][j]);
    }
  }
  // epilogue
  #pragma unroll
  for (int i = 0; i < 4; ++i) {
    int gr = row0 + ty * 4 + i;
    if (gr >= M) continue;
    long rrow = 0;
    if (HAS_RES) rrow = ridx ? (long)ridx[gr] : (long)gr;
    #pragma unroll
    for (int j = 0; j < CW; ++j) {
      int c = tx * CW + j;
      float v = acc[i][j];
      if (HAS_BIAS) v += bias[c];
      if (DO_ELU) v = (v > 0.f) ? v : (__expf(v) - 1.f);
      if (HAS_RES) v += Res[rrow * NC + c];
      C[(long)gr * NC + c] = v;
    }
  }
}

// ---------------- per-node score projections: as = H1@a_s, an = H1@a_n -------------
__global__ __launch_bounds__(256) void proj_kernel(
    const float* __restrict__ H1, const float* __restrict__ a_s, const float* __restrict__ a_n,
    float* __restrict__ as_o, float* __restrict__ an_o, int M)
{
  int wid  = (int)((blockIdx.x * 256 + threadIdx.x) >> 6);
  int lane = threadIdx.x & 63;
  if (wid >= M) return;
  float2 h  = *reinterpret_cast<const float2*>(H1 + (long)wid * KD + lane * 2);
  float2 vs = *reinterpret_cast<const float2*>(a_s + lane * 2);
  float2 vn = *reinterpret_cast<const float2*>(a_n + lane * 2);
  float ps = h.x * vs.x + h.y * vs.y;
  float pn = h.x * vn.x + h.y * vn.y;
  #pragma unroll
  for (int o = 32; o > 0; o >>= 1) { ps += __shfl_xor(ps, o, 64); pn += __shfl_xor(pn, o, 64); }
  if (lane == 0) { as_o[wid] = ps; an_o[wid] = pn; }
}

// ---------------- needed-dst flags -------------
__global__ void flags_kernel(const int* __restrict__ ui, const int* __restrict__ ii, int B,
                             int* __restrict__ nfu, int* __restrict__ nfb)
{
  int i = blockIdx.x * blockDim.x + threadIdx.x;
  if (i < B) { nfu[ui[i]] = 1; nfb[ii[i]] = 1; }
}

// ---------------- omega edge weights -------------
__global__ void uw_kernel(const float* __restrict__ gc, const float* __restrict__ omega,
                          int E, float* __restrict__ uw)
{
  int e = blockIdx.x * blockDim.x + threadIdx.x;
  if (e < E) uw[e] = gc[(long)e*3+0]*omega[0] + gc[(long)e*3+1]*omega[1] + gc[(long)e*3+2]*omega[2];
}

// ---------------- grouping pass 1: per-dst degree (gated) -------------
__global__ __launch_bounds__(256) void count_kernel(
    const int* __restrict__ dst, const int* __restrict__ flag,
    int* __restrict__ deg, int E)
{
  int e = blockIdx.x * 256 + threadIdx.x;
  if (e >= E) return;
  int d = dst[e];
  if (flag[d]) atomicAdd(&deg[d], 1);
}

// ---------------- grouping pass 2: assign segment offsets + compact dst list ----
__global__ __launch_bounds__(256) void offset_kernel(
    const int* __restrict__ flag, const int* __restrict__ deg,
    int* __restrict__ offs, int* __restrict__ cur,
    int* __restrict__ dlist, int* __restrict__ cnt,
    float* __restrict__ Hout, int N)
{
  int i = blockIdx.x * 256 + threadIdx.x;
  if (i >= N || !flag[i]) return;
  int dg = deg[i];
  if (dg == 0) {
    // flagged node with no incoming edges: reference yields a zero row
    float4 z = make_float4(0.f, 0.f, 0.f, 0.f);
    float4* r = reinterpret_cast<float4*>(Hout + (long)i * KD);
    #pragma unroll
    for (int j = 0; j < KD / 4; ++j) r[j] = z;
    return;
  }
  int o = atomicAdd(&cnt[0], dg);
  int l = atomicAdd(&cnt[1], 1);
  offs[i] = o;
  cur[i]  = o;
  dlist[l] = i;
}

// ---------------- grouping pass 3: scatter (src, leaky score) into groups ----
__global__ __launch_bounds__(256) void scatter_kernel(
    const int* __restrict__ src, const int* __restrict__ dst,
    const int* __restrict__ flag,
    const float* __restrict__ as_, const float* __restrict__ an_,
    const float* __restrict__ uw, int* __restrict__ cur,
    int* __restrict__ esrc, float* __restrict__ esc, int E)
{
  int e = blockIdx.x * 256 + threadIdx.x;
  if (e >= E) return;
  int d = dst[e];
  if (!flag[d]) return;
  int s = src[e];
  float sc = as_[d] + an_[s];
  if (uw) sc *= uw[e];
  sc = (sc >= 0.f) ? sc : 0.2f * sc;   // leaky_relu 0.2
  int pos = atomicAdd(&cur[d], 1);
  esrc[pos] = s;
  esc[pos]  = sc;
}

// ---------------- wave-per-dst softmax + aggregation (no feature atomics) ----
__global__ __launch_bounds__(256) void aggr_kernel(
    const int* __restrict__ dlist, const int* __restrict__ cnt,
    const int* __restrict__ offs, const int* __restrict__ deg,
    const int* __restrict__ esrc, const float* __restrict__ esc,
    const float* __restrict__ H1, float* __restrict__ Hout)
{
  int wid  = (int)((blockIdx.x * 256 + threadIdx.x) >> 6);
  int lane = threadIdx.x & 63;
  if (wid >= cnt[1]) return;
  int d  = dlist[wid];
  int st = offs[d];
  int n  = deg[d];
  // segment max
  float m = -3.4e38f;
  for (int i = lane; i < n; i += 64) m = fmaxf(m, esc[st + i]);
  #pragma unroll
  for (int o = 32; o; o >>= 1) m = fmaxf(m, __shfl_xor(m, o, 64));
  // segment sum of exp
  float s = 0.f;
  for (int i = lane; i < n; i += 64) s += __expf(esc[st + i] - m);
  #pragma unroll
  for (int o = 32; o; o >>= 1) s += __shfl_xor(s, o, 64);
  float inv = 1.f / s;
  // weighted aggregation: each lane owns 2 columns; rows read coalesced
  float ax = 0.f, ay = 0.f;
  int i = 0;
  for (; i + 2 <= n; i += 2) {
    float a0 = __expf(esc[st + i]     - m);
    float a1 = __expf(esc[st + i + 1] - m);
    const float2 h0 = *reinterpret_cast<const float2*>(H1 + (long)esrc[st + i]     * KD + lane * 2);
    const float2 h1 = *reinterpret_cast<const float2*>(H1 + (long)esrc[st + i + 1] * KD + lane * 2);
    ax = fmaf(h0.x, a0, ax); ay = fmaf(h0.y, a0, ay);
    ax = fmaf(h1.x, a1, ax); ay = fmaf(h1.y, a1, ay);
  }
  if (i < n) {
    float a0 = __expf(esc[st + i] - m);
    const float2 h0 = *reinterpret_cast<const float2*>(H1 + (long)esrc[st + i] * KD + lane * 2);
    ax = fmaf(h0.x, a0, ax); ay = fmaf(h0.y, a0, ay);
  }
  *reinterpret_cast<float2*>(Hout + (long)d * KD + lane * 2) = make_float2(ax * inv, ay * inv);
}

// ---------------- final: dot + biases + sigmoid -------------
__global__ __launch_bounds__(256) void final_kernel(
    const float* __restrict__ Ug, const float* __restrict__ Bg,
    const int* __restrict__ ui, const int* __restrict__ ii,
    const float* __restrict__ bias_u, const float* __restrict__ bias_b,
    const float* __restrict__ bx, float* __restrict__ out, int B)
{
  int wid  = (int)((blockIdx.x * 256 + threadIdx.x) >> 6);
  int lane = threadIdx.x & 63;
  if (wid >= B) return;
  float v = Ug[(long)wid * 64 + lane] * Bg[(long)wid * 64 + lane];
  #pragma unroll
  for (int o = 32; o > 0; o >>= 1) v += __shfl_xor(v, o, 64);
  if (lane == 0) {
    float raw = v + bias_u[ui[wid]] + bias_b[ii[wid]] + bx[0];
    out[wid] = 4.f / (1.f + __expf(-raw)) + 1.f;
  }
}

extern "C" void kernel_launch(void* const* d_in, const int* in_sizes, int n_in,
                              void* d_out, int out_size, void* d_ws, size_t ws_size,
                              hipStream_t stream)
{
  const int*   ui    = (const int*)  d_in[0];
  const int*   ii    = (const int*)  d_in[1];
  const float* S_u   = (const float*)d_in[2];
  const float* S_b   = (const float*)d_in[3];
  const int*   eu    = (const int*)  d_in[4];
  const int*   eb    = (const int*)  d_in[5];
  const float* gc    = (const float*)d_in[6];
  const float* W1_u  = (const float*)d_in[7];
  const float* a_s_u = (const float*)d_in[8];
  const float* a_n_u = (const float*)d_in[9];
  const float* W1_b  = (const float*)d_in[10];
  const float* a_s_b = (const float*)d_in[11];
  const float* a_n_b = (const float*)d_in[12];
  const float* omega = (const float*)d_in[13];
  const float* W_u2  = (const float*)d_in[14];
  const float* W_us2w= (const float*)d_in[15];
  const float* W_us2b= (const float*)d_in[16];
  const float* W_b2  = (const float*)d_in[17];
  const float* W_bs2w= (const float*)d_in[18];
  const float* W_bs2b= (const float*)d_in[19];
  const float* W_u3  = (const float*)d_in[20];
  const float* W_b3  = (const float*)d_in[21];
  const float* H_u4  = (const float*)d_in[22];
  const float* H_b4  = (const float*)d_in[23];
  const float* bias_u= (const float*)d_in[24];
  const float* bias_b= (const float*)d_in[25];
  const float* b_x   = (const float*)d_in[26];
  float* out = (float*)d_out;

  const int B  = in_sizes[0];
  const int NU = in_sizes[2] / KD;
  const int NI = in_sizes[3] / KD;
  const int EU = in_sizes[4] / 2;
  const int EB = in_sizes[5] / 2;

  char* w = (char*)d_ws;
  auto alloc = [&](size_t bytes) -> void* {
    void* r = (void*)w;
    w += (bytes + 255) & ~(size_t)255;
    return r;
  };
  // ---- zero-initialized region (one small memset per call) ----
  int* deg_u = (int*)alloc((size_t)NU * 4);
  int* deg_b = (int*)alloc((size_t)NI * 4);
  int* nfu   = (int*)alloc((size_t)NU * 4);
  int* nfb   = (int*)alloc((size_t)NI * 4);
  int* cnt   = (int*)alloc(16 * 4);          // [0,1]=user {edges,dsts}, [2,3]=item
  size_t zbytes = (size_t)(w - (char*)d_ws);
  // ---- scratch (fully written before read each call) ----
  int*   offs_u = (int*)  alloc((size_t)NU * 4);
  int*   cur_u  = (int*)  alloc((size_t)NU * 4);
  int*   offs_b = (int*)  alloc((size_t)NI * 4);
  int*   cur_b  = (int*)  alloc((size_t)NI * 4);
  int*   dl_u   = (int*)  alloc((size_t)B * 4);
  int*   dl_b   = (int*)  alloc((size_t)B * 4);
  int*   esrc_u = (int*)  alloc((size_t)EU * 4);
  float* esc_u  = (float*)alloc((size_t)EU * 4);
  int*   esrc_b = (int*)  alloc((size_t)EB * 4);
  float* esc_b  = (float*)alloc((size_t)EB * 4);
  float* H1u  = (float*)alloc((size_t)NU * KD * 4);
  float* H1b  = (float*)alloc((size_t)NI * KD * 4);
  float* Hu2  = (float*)alloc((size_t)NU * KD * 4);
  float* Hb2  = (float*)alloc((size_t)NI * KD * 4);
  float* asu  = (float*)alloc((size_t)NU * 4);
  float* anu  = (float*)alloc((size_t)NU * 4);
  float* asb  = (float*)alloc((size_t)NI * 4);
  float* anb  = (float*)alloc((size_t)NI * 4);
  float* uwv  = (float*)alloc((size_t)EB * 4);
  float* Hu3g = (float*)alloc((size_t)B * KD * 4);
  float* Hb3g = (float*)alloc((size_t)B * KD * 4);
  float* Ug   = (float*)alloc((size_t)B * 64 * 4);
  float* Bg   = (float*)alloc((size_t)B * 64 * 4);
  (void)ws_size; (void)n_in; (void)out_size;

  hipMemsetAsync(d_ws, 0, zbytes, stream);

  flags_kernel<<<(B + 255) / 256, 256, 0, stream>>>(ui, ii, B, nfu, nfb);
  uw_kernel<<<(EB + 255) / 256, 256, 0, stream>>>(gc, omega, EB, uwv);

  gemm_k128<128,false,false,false,false><<<(NU + 63) / 64, 256, 0, stream>>>(
      S_u, W1_u, nullptr, nullptr, nullptr, nullptr, nullptr, nullptr, NU, H1u);
  gemm_k128<128,false,false,false,false><<<(NI + 63) / 64, 256, 0, stream>>>(
      S_b, W1_b, nullptr, nullptr, nullptr, nullptr, nullptr, nullptr, NI, H1b);

  proj_kernel<<<(NU + 3) / 4, 256, 0, stream>>>(H1u, a_s_u, a_n_u, asu, anu, NU);
  proj_kernel<<<(NI + 3) / 4, 256, 0, stream>>>(H1b, a_s_b, a_n_b, asb, anb, NI);

  count_kernel<<<(EU + 255) / 256, 256, 0, stream>>>(eu + EU, nfu, deg_u, EU);
  count_kernel<<<(EB + 255) / 256, 256, 0, stream>>>(eb + EB, nfb, deg_b, EB);

  offset_kernel<<<(NU + 255) / 256, 256, 0, stream>>>(nfu, deg_u, offs_u, cur_u, dl_u, cnt + 0, Hu2, NU);
  offset_kernel<<<(NI + 255) / 256, 256, 0, stream>>>(nfb, deg_b, offs_b, cur_b, dl_b, cnt + 2, Hb2, NI);

  scatter_kernel<<<(EU + 255) / 256, 256, 0, stream>>>(eu, eu + EU, nfu, asu, anu, nullptr, cur_u, esrc_u, esc_u, EU);
  scatter_kernel<<<(EB + 255) / 256, 256, 0, stream>>>(eb, eb + EB, nfb, asb, anb, uwv, cur_b, esrc_b, esc_b, EB);

  aggr_kernel<<<(B * 64 + 255) / 256, 256, 0, stream>>>(dl_u, cnt + 0, offs_u, deg_u, esrc_u, esc_u, H1u, Hu2);
  aggr_kernel<<<(B * 64 + 255) / 256, 256, 0, stream>>>(dl_b, cnt + 2, offs_b, deg_b, esrc_b, esc_b, H1b, Hb2);

  gemm_k128<128,true,true,true,false><<<(B + 63) / 64, 256, 0, stream>>>(
      Hu2, W_u2, S_u, W_us2w, W_us2b, nullptr, ui, nullptr, B, Hu3g);
  gemm_k128<128,true,true,true,false><<<(B + 63) / 64, 256, 0, stream>>>(
      Hb2, W_b2, S_b, W_bs2w, W_bs2b, nullptr, ii, nullptr, B, Hb3g);

  gemm_k128<64,false,false,true,true><<<(B + 63) / 64, 256, 0, stream>>>(
      Hu3g, W_u3, nullptr, nullptr, nullptr, H_u4, nullptr, ui, B, Ug);
  gemm_k128<64,false,false,true,true><<<(B + 63) / 64, 256, 0, stream>>>(
      Hb3g, W_b3, nullptr, nullptr, nullptr, H_b4, nullptr, ii, B, Bg);

  final_kernel<<<(B + 3) / 4, 256, 0, stream>>>(Ug, Bg, ui, ii, bias_u, bias_b, b_x, out, B);
}